// Round 3
// baseline (741.252 us; speedup 1.0000x reference)
//
#include <hip/hip_runtime.h>

#define N_FEAT 128
#define F1 16
#define F2 2
#define BSHIFT 7
#define BNODES 128        // nodes per bucket (dst >> 7)
#define CHUNK 8192        // edges per bucketing block
#define MAXNB 1024        // scan capacity (NB = 782)

// ---------------- degree histogram over dst (no-return atomics: fast) --------
__global__ void deg_kernel(const int* __restrict__ col, int E, int* __restrict__ deg) {
    int i = blockIdx.x * blockDim.x + threadIdx.x;
    if (i < E) atomicAdd(&deg[col[i]], 1);
}

__global__ void dinv_kernel(const int* __restrict__ deg, float* __restrict__ dinv, int N) {
    int i = blockIdx.x * blockDim.x + threadIdx.x;
    if (i < N) dinv[i] = rsqrtf((float)(deg[i] + 1));  // +1 self loop
}

// ---------------- layer-1 GEMM: hs[r,f] = dinv[r] * sum_k x[r,k]*W1[k,f] -----
__global__ __launch_bounds__(256) void gemm1_kernel(
    const float* __restrict__ x, const float* __restrict__ W1,
    const float* __restrict__ dinv, float* __restrict__ hs, int N) {
    __shared__ float ws[N_FEAT * F1];
    __shared__ float xs[16][N_FEAT];
    int t = threadIdx.x;
    for (int i = t; i < N_FEAT * F1; i += 256) ws[i] = W1[i];
    int row0 = blockIdx.x * 16;
    for (int i = t; i < 16 * N_FEAT; i += 256) {
        int r = i >> 7, k = i & 127;
        int row = row0 + r;
        xs[r][k] = (row < N) ? x[row * N_FEAT + k] : 0.f;
    }
    __syncthreads();
    int rr = t >> 4, f = t & 15;
    int row = row0 + rr;
    if (row < N) {
        float acc = 0.f;
#pragma unroll
        for (int k = 0; k < N_FEAT; ++k) acc += xs[rr][k] * ws[k * F1 + f];
        hs[row * F1 + f] = acc * dinv[row];
    }
}

// ---------------- bucket histogram (LDS-aggregated) --------------------------
__global__ __launch_bounds__(256) void bhist_kernel(const int* __restrict__ coli, int E,
                                                    int NB, int* __restrict__ bucketCount) {
    __shared__ int h[MAXNB];
    int t = threadIdx.x;
    for (int i = t; i < NB; i += 256) h[i] = 0;
    __syncthreads();
    int s = blockIdx.x * CHUNK;
    int e = min(s + CHUNK, E);
    for (int i = s + t; i < e; i += 256) atomicAdd(&h[coli[i] >> BSHIFT], 1);
    __syncthreads();
    for (int i = t; i < NB; i += 256) {
        int v = h[i];
        if (v) atomicAdd(&bucketCount[i], v);
    }
}

// ---------------- exclusive scan of bucket counts (1 block) ------------------
__global__ __launch_bounds__(MAXNB) void bscan_kernel(const int* __restrict__ bucketCount,
                                                      int* __restrict__ off,
                                                      int* __restrict__ cursor, int NB, int E) {
    __shared__ int s[MAXNB];
    int t = threadIdx.x;
    int v = (t < NB) ? bucketCount[t] : 0;
    s[t] = v;
    __syncthreads();
    for (int o = 1; o < MAXNB; o <<= 1) {
        int u = (t >= o) ? s[t - o] : 0;
        __syncthreads();
        s[t] += u;
        __syncthreads();
    }
    if (t < NB) {
        int x = s[t] - v;   // exclusive
        off[t] = x;
        cursor[t] = x;
    }
    if (t == 0) off[NB] = E;
}

// ---------------- bucketed fill: one reservation per (block,bucket) ----------
__global__ __launch_bounds__(256) void bfill_kernel(const int* __restrict__ rowi,
                                                    const int* __restrict__ coli,
                                                    int* __restrict__ cursor,
                                                    unsigned int* __restrict__ ebuf,
                                                    int E, int NB) {
    __shared__ int h[MAXNB];
    __shared__ int baseL[MAXNB];
    int t = threadIdx.x;
    for (int i = t; i < NB; i += 256) h[i] = 0;
    __syncthreads();
    int s0 = blockIdx.x * CHUNK;
    int e0 = min(s0 + CHUNK, E);
    for (int i = s0 + t; i < e0; i += 256) atomicAdd(&h[coli[i] >> BSHIFT], 1);
    __syncthreads();
    for (int i = t; i < NB; i += 256) {
        int v = h[i];
        baseL[i] = v ? atomicAdd(&cursor[i], v) : 0;
        h[i] = 0;   // reuse as local rank counter
    }
    __syncthreads();
    for (int i = s0 + t; i < e0; i += 256) {
        int c = coli[i];
        int b = c >> BSHIFT;
        int r = atomicAdd(&h[b], 1);                 // LDS: fast
        ebuf[baseL[b] + r] = ((unsigned)rowi[i] << BSHIFT) | (unsigned)(c & (BNODES - 1));
    }
}

// ---------------- phase B: layer-1 aggregate in LDS + fused relu/W2 ----------
__global__ __launch_bounds__(256) void phaseB_kernel(
    const unsigned int* __restrict__ ebuf, const int* __restrict__ off,
    const float* __restrict__ hs, const float* __restrict__ dinv,
    const float* __restrict__ b1, const float* __restrict__ W2,
    float* __restrict__ hs2, int N) {
    __shared__ float accL[BNODES * 17];   // +1 pad per row
    __shared__ unsigned int eT[256];
    __shared__ float b1s[F1];
    __shared__ float w2s[F1 * F2];
    int t = threadIdx.x;
    if (t < F1) b1s[t] = b1[t];
    if (t < F1 * F2) w2s[t] = W2[t];
    for (int i = t; i < BNODES * 17; i += 256) accL[i] = 0.f;
    int b = blockIdx.x;
    int s = off[b], e = off[b + 1];
    int g = t >> 4, f = t & 15;
    __syncthreads();
    for (int tile = s; tile < e; tile += 256) {
        int n = min(256, e - tile);
        if (t < n) eT[t] = ebuf[tile + t];
        __syncthreads();
        for (int it = 0; it < 16; ++it) {
            int idx = it * 16 + g;
            if (idx < n) {
                unsigned u = eT[idx];
                int src = (int)(u >> BSHIFT);
                int dl = (int)(u & (BNODES - 1));
                atomicAdd(&accL[dl * 17 + f], hs[src * F1 + f]);   // ds_add_f32
            }
        }
        __syncthreads();
    }
    if (t < BNODES) {
        int node = b * BNODES + t;
        if (node < N) {
            float di = dinv[node];
            float h0 = 0.f, h1 = 0.f;
#pragma unroll
            for (int k = 0; k < F1; ++k) {
                float v = di * (accL[t * 17 + k] + hs[node * F1 + k]) + b1s[k];
                float o = fmaxf(v, 0.f);
                h0 += o * w2s[k * F2 + 0];
                h1 += o * w2s[k * F2 + 1];
            }
            float2 r;
            r.x = h0 * di;
            r.y = h1 * di;
            ((float2*)hs2)[node] = r;
        }
    }
}

// ---------------- phase C: layer-2 aggregate in LDS + finalize ---------------
__global__ __launch_bounds__(256) void phaseC_kernel(
    const unsigned int* __restrict__ ebuf, const int* __restrict__ off,
    const float* __restrict__ hs2, const float* __restrict__ dinv,
    const float* __restrict__ b2, float* __restrict__ out, int N) {
    __shared__ float a2[BNODES * 2];
    int t = threadIdx.x;
    for (int i = t; i < BNODES * 2; i += 256) a2[i] = 0.f;
    int b = blockIdx.x;
    int s = off[b], e = off[b + 1];
    __syncthreads();
    for (int i = s + t; i < e; i += 256) {
        unsigned u = ebuf[i];
        int src = (int)(u >> BSHIFT);
        int dl = (int)(u & (BNODES - 1));
        float2 v = ((const float2*)hs2)[src];
        atomicAdd(&a2[dl * 2 + 0], v.x);
        atomicAdd(&a2[dl * 2 + 1], v.y);
    }
    __syncthreads();
    if (t < BNODES) {
        int node = b * BNODES + t;
        if (node < N) {
            float di = dinv[node];
            float2 sv = ((const float2*)hs2)[node];
            float2 o;
            o.x = di * (a2[t * 2 + 0] + sv.x) + b2[0];
            o.y = di * (a2[t * 2 + 1] + sv.y) + b2[1];
            ((float2*)out)[node] = o;
        }
    }
}

extern "C" void kernel_launch(void* const* d_in, const int* in_sizes, int n_in,
                              void* d_out, int out_size, void* d_ws, size_t ws_size,
                              hipStream_t stream) {
    const float* x  = (const float*)d_in[0];
    const int*   ei = (const int*)d_in[1];
    const float* W1 = (const float*)d_in[2];
    const float* b1 = (const float*)d_in[3];
    const float* W2 = (const float*)d_in[4];
    const float* b2 = (const float*)d_in[5];
    int N = in_sizes[0] / N_FEAT;
    int E = in_sizes[1] / 2;
    const int* rowi = ei;        // src
    const int* coli = ei + E;    // dst
    float* out = (float*)d_out;

    int NB = (N + BNODES - 1) / BNODES;   // 782

    // workspace layout, 1024-element padded regions
    size_t NP = ((size_t)N + 1023) & ~(size_t)1023;
    size_t EP = ((size_t)E + 1023) & ~(size_t)1023;
    char* w = (char*)d_ws;
    int*          deg    = (int*)w;            w += NP * 4;
    float*        dinv   = (float*)w;          w += NP * 4;
    float*        hs     = (float*)w;          w += NP * F1 * 4;
    float*        hs2    = (float*)w;          w += NP * F2 * 4;
    int*          bCount = (int*)w;            w += MAXNB * 4;
    int*          off    = (int*)w;            w += (MAXNB + 1) * 4;
    int*          cursor = (int*)w;            w += MAXNB * 4;
    unsigned int* ebuf   = (unsigned int*)w;   w += EP * 4;

    int nbE = (E + 255) / 256;
    int nbChunk = (E + CHUNK - 1) / CHUNK;    // 391

    hipMemsetAsync(deg, 0, (size_t)N * sizeof(int), stream);
    hipMemsetAsync(bCount, 0, (size_t)NB * sizeof(int), stream);

    deg_kernel<<<nbE, 256, 0, stream>>>(coli, E, deg);
    dinv_kernel<<<(N + 255) / 256, 256, 0, stream>>>(deg, dinv, N);
    gemm1_kernel<<<(N + 15) / 16, 256, 0, stream>>>(x, W1, dinv, hs, N);

    bhist_kernel<<<nbChunk, 256, 0, stream>>>(coli, E, NB, bCount);
    bscan_kernel<<<1, MAXNB, 0, stream>>>(bCount, off, cursor, NB, E);
    bfill_kernel<<<nbChunk, 256, 0, stream>>>(rowi, coli, cursor, ebuf, E, NB);

    phaseB_kernel<<<NB, 256, 0, stream>>>(ebuf, off, hs, dinv, b1, W2, hs2, N);
    phaseC_kernel<<<NB, 256, 0, stream>>>(ebuf, off, hs2, dinv, b2, out, N);
}

// Round 5
// 652.643 us; speedup vs baseline: 1.1358x; 1.1358x over previous
//
#include <hip/hip_runtime.h>

#define N_FEAT 128
#define F1 16
#define F2 2
#define BSHIFT 7
#define BNODES 128        // nodes per bucket
#define MAXNB 1024        // scan capacity (NB = 782)
#define FCHUNK 8192       // edges per bfill block

// ---------------- degree histogram over dst (no-return int atomics) ----------
__global__ void deg_kernel(const int* __restrict__ col, int E, int* __restrict__ deg) {
    int i = blockIdx.x * blockDim.x + threadIdx.x;
    if (i < E) atomicAdd(&deg[col[i]], 1);
}

// ---------------- bucket counts from deg + exclusive scan (1 block) ----------
__global__ __launch_bounds__(MAXNB) void bscan_kernel(const int* __restrict__ deg,
                                                      int* __restrict__ off,
                                                      int* __restrict__ cursor,
                                                      int NB, int E, int N) {
    __shared__ int s[MAXNB];
    int t = threadIdx.x;
    int v = 0;
    if (t < NB) {
        int base = t * BNODES;
        int lim = min(BNODES, N - base);
        for (int k = 0; k < lim; ++k) v += deg[base + k];
    }
    s[t] = v;
    __syncthreads();
    for (int o = 1; o < MAXNB; o <<= 1) {
        int u = (t >= o) ? s[t - o] : 0;
        __syncthreads();
        s[t] += u;
        __syncthreads();
    }
    if (t < NB) {
        int x = s[t] - v;   // exclusive
        off[t] = x;
        cursor[t] = x;
    }
    if (t == 0) off[NB] = E;
}

// ---------------- bucketed fill: one reservation per (block,bucket) ----------
__global__ __launch_bounds__(256) void bfill_kernel(const int* __restrict__ rowi,
                                                    const int* __restrict__ coli,
                                                    int* __restrict__ cursor,
                                                    unsigned int* __restrict__ ebuf,
                                                    int E, int NB) {
    __shared__ int h[MAXNB];
    __shared__ int baseL[MAXNB];
    int t = threadIdx.x;
    for (int i = t; i < NB; i += 256) h[i] = 0;
    __syncthreads();
    int s0 = blockIdx.x * FCHUNK;
    int e0 = min(s0 + FCHUNK, E);
    for (int i = s0 + t; i < e0; i += 256) atomicAdd(&h[coli[i] >> BSHIFT], 1);
    __syncthreads();
    for (int i = t; i < NB; i += 256) {
        int v = h[i];
        baseL[i] = v ? atomicAdd(&cursor[i], v) : 0;
        h[i] = 0;   // reuse as local rank
    }
    __syncthreads();
    for (int i = s0 + t; i < e0; i += 256) {
        int c = coli[i];
        int b = c >> BSHIFT;
        int r = atomicAdd(&h[b], 1);                 // LDS returning atomic: fast
        ebuf[baseL[b] + r] = ((unsigned)rowi[i] << BSHIFT) | (unsigned)(c & (BNODES - 1));
    }
}

// ---------------- layer-1 GEMM: hs[r,f] = dinv[r] * sum_k x[r,k]*W1[k,f] -----
__global__ __launch_bounds__(256) void gemm1_kernel(
    const float* __restrict__ x, const float* __restrict__ W1,
    const int* __restrict__ deg, float* __restrict__ hs, int N) {
    __shared__ float ws[N_FEAT * F1];
    __shared__ float xs[16][132];       // padded
    int t = threadIdx.x;
    const float4* W14 = (const float4*)W1;
    for (int i = t; i < 512; i += 256) ((float4*)ws)[i] = W14[i];
    int row0 = blockIdx.x * 16;
    for (int i = t; i < 512; i += 256) {
        int r = i >> 5, k4 = i & 31;
        int row = row0 + r;
        float4 v = (row < N) ? ((const float4*)x)[row * 32 + k4] : make_float4(0.f, 0.f, 0.f, 0.f);
        *(float4*)&xs[r][k4 * 4] = v;
    }
    __syncthreads();
    int rr = t >> 4, f = t & 15;
    int row = row0 + rr;
    if (row < N) {
        float acc = 0.f;
#pragma unroll
        for (int k = 0; k < N_FEAT; ++k) acc += xs[rr][k] * ws[k * F1 + f];
        hs[row * F1 + f] = acc * rsqrtf((float)(deg[row] + 1));
    }
}

// ---------------- phase B: segmented bucket aggregate -> partial tiles -------
__global__ __launch_bounds__(256) void phaseB_kernel(
    const unsigned int* __restrict__ ebuf, const int* __restrict__ off,
    const float* __restrict__ hs, float* __restrict__ accp,
    int S, int NPitch) {
    __shared__ float accL[BNODES * 17];
    __shared__ unsigned int eT[256];
    int t = threadIdx.x;
    int b = blockIdx.x / S;
    int seg = blockIdx.x - b * S;
    int s0 = off[b], s1 = off[b + 1];
    int cnt = s1 - s0;
    int len = (cnt + S - 1) / S;
    int base = s0 + seg * len;
    int end = min(base + len, s1);
    for (int i = t; i < BNODES * 17; i += 256) accL[i] = 0.f;
    int g = t >> 4, f = t & 15;
    for (int tile = base; tile < end; tile += 256) {
        int n = min(256, end - tile);
        __syncthreads();
        if (t < n) eT[t] = ebuf[tile + t];
        __syncthreads();
        for (int it = 0; it < 16; it += 4) {
            float v[4];
            int dl[4];
#pragma unroll
            for (int j = 0; j < 4; ++j) {
                int idx = (it + j) * 16 + g;
                if (idx < n) {
                    unsigned u = eT[idx];            // broadcast to 16 f-lanes
                    dl[j] = (int)(u & (BNODES - 1));
                    v[j] = hs[(u >> BSHIFT) * F1 + f];   // 64B line per edge
                } else { dl[j] = -1; v[j] = 0.f; }
            }
#pragma unroll
            for (int j = 0; j < 4; ++j)
                if (dl[j] >= 0) atomicAdd(&accL[dl[j] * 17 + f], v[j]);
        }
    }
    __syncthreads();
    float* dst = accp + ((size_t)seg * NPitch + (size_t)b * BNODES) * F1;
    for (int i = t; i < BNODES * F1; i += 256) {
        int row = i >> 4, ff = i & 15;
        dst[i] = accL[row * 17 + ff];                // coalesced, block-exclusive
    }
}

// ---------------- layer 2 prep: sum partials + self, relu, x W2 --------------
__global__ __launch_bounds__(256) void layer2_kernel(
    const float* __restrict__ accp, const float* __restrict__ hs,
    const int* __restrict__ deg, const float* __restrict__ b1,
    const float* __restrict__ W2, float* __restrict__ hs2,
    int S, int NPitch, int N) {
    __shared__ float w2s[F1 * F2];
    __shared__ float b1s[F1];
    int t = threadIdx.x;
    if (t < F1 * F2) w2s[t] = W2[t];
    if (t < F1) b1s[t] = b1[t];
    __syncthreads();
    int i = blockIdx.x * blockDim.x + t;
    if (i >= N) return;
    float di = rsqrtf((float)(deg[i] + 1));
    float4 a[4];
    const float4* s4 = (const float4*)(hs + (size_t)i * F1);
#pragma unroll
    for (int q = 0; q < 4; ++q) a[q] = s4[q];
    for (int s = 0; s < S; ++s) {
        const float4* p = (const float4*)(accp + ((size_t)s * NPitch + i) * F1);
#pragma unroll
        for (int q = 0; q < 4; ++q) {
            float4 v = p[q];
            a[q].x += v.x; a[q].y += v.y; a[q].z += v.z; a[q].w += v.w;
        }
    }
    float h0 = 0.f, h1 = 0.f;
#pragma unroll
    for (int q = 0; q < 4; ++q) {
        float vv[4] = {a[q].x, a[q].y, a[q].z, a[q].w};
#pragma unroll
        for (int u = 0; u < 4; ++u) {
            int f = q * 4 + u;
            float o = fmaxf(di * vv[u] + b1s[f], 0.f);
            h0 += o * w2s[f * F2 + 0];
            h1 += o * w2s[f * F2 + 1];
        }
    }
    float2 r;
    r.x = h0 * di;
    r.y = h1 * di;
    ((float2*)hs2)[i] = r;
}

// ---------------- phase C: segmented layer-2 aggregate -> partial tiles ------
__global__ __launch_bounds__(256) void phaseC_kernel(
    const unsigned int* __restrict__ ebuf, const int* __restrict__ off,
    const float* __restrict__ hs2, float* __restrict__ outp,
    int S, int NPitch) {
    __shared__ float o2[BNODES * 2];
    int t = threadIdx.x;
    int b = blockIdx.x / S;
    int seg = blockIdx.x - b * S;
    int s0 = off[b], s1 = off[b + 1];
    int cnt = s1 - s0;
    int len = (cnt + S - 1) / S;
    int base = s0 + seg * len;
    int end = min(base + len, s1);
    for (int i = t; i < BNODES * 2; i += 256) o2[i] = 0.f;
    __syncthreads();
    for (int i = base + t; i < end; i += 256) {     // independent iters: pipelines
        unsigned u = ebuf[i];
        float2 v = ((const float2*)hs2)[u >> BSHIFT];
        int dl = (int)(u & (BNODES - 1));
        atomicAdd(&o2[dl * 2 + 0], v.x);
        atomicAdd(&o2[dl * 2 + 1], v.y);
    }
    __syncthreads();
    float* dst = outp + ((size_t)seg * NPitch + (size_t)b * BNODES) * F2;
    if (t < BNODES * 2) dst[t] = o2[t];
}

// ---------------- finalize layer 2 ------------------------------------------
__global__ void fin2_kernel(const float* __restrict__ outp, const float* __restrict__ hs2,
                            const int* __restrict__ deg, const float* __restrict__ b2,
                            float* __restrict__ out, int S, int NPitch, int N) {
    int i = blockIdx.x * blockDim.x + threadIdx.x;
    if (i >= N) return;
    float di = rsqrtf((float)(deg[i] + 1));
    float2 s = ((const float2*)hs2)[i];
    float a0 = s.x, a1 = s.y;
    for (int ss = 0; ss < S; ++ss) {
        float2 p = ((const float2*)(outp + (size_t)ss * NPitch * F2))[i];
        a0 += p.x; a1 += p.y;
    }
    float2 o;
    o.x = di * a0 + b2[0];
    o.y = di * a1 + b2[1];
    ((float2*)out)[i] = o;
}

extern "C" void kernel_launch(void* const* d_in, const int* in_sizes, int n_in,
                              void* d_out, int out_size, void* d_ws, size_t ws_size,
                              hipStream_t stream) {
    const float* x  = (const float*)d_in[0];
    const int*   ei = (const int*)d_in[1];
    const float* W1 = (const float*)d_in[2];
    const float* b1 = (const float*)d_in[3];
    const float* W2 = (const float*)d_in[4];
    const float* b2 = (const float*)d_in[5];
    int N = in_sizes[0] / N_FEAT;
    int E = in_sizes[1] / 2;
    const int* rowi = ei;        // src
    const int* coli = ei + E;    // dst
    float* out = (float*)d_out;

    int NB = (N + BNODES - 1) / BNODES;   // 782

    size_t NP = ((size_t)N + 1023) & ~(size_t)1023;
    size_t EP = ((size_t)E + 1023) & ~(size_t)1023;

    // fixed regions
    char* w = (char*)d_ws;
    int*          deg    = (int*)w;            w += NP * 4;
    int*          off    = (int*)w;            w += (MAXNB + 1) * 4;
    int*          cursor = (int*)w;            w += MAXNB * 4;
    float*        hs     = (float*)w;          w += NP * F1 * 4;
    float*        hs2    = (float*)w;          w += NP * F2 * 4;
    unsigned int* ebuf   = (unsigned int*)w;   w += EP * 4;

    // segment count by remaining workspace (accp: NP*F1*4, outp: NP*F2*4 per seg)
    size_t used = (size_t)(w - (char*)d_ws);
    size_t perSeg = NP * (F1 + F2) * 4;
    int S = (int)((ws_size > used) ? ((ws_size - used) / perSeg) : 1);
    if (S > 4) S = 4;
    if (S < 1) S = 1;
    float* accp = (float*)w;                   w += (size_t)S * NP * F1 * 4;
    float* outp = (float*)w;

    int nbE = (E + 255) / 256;
    int nbN = (N + 255) / 256;

    hipMemsetAsync(deg, 0, (size_t)N * sizeof(int), stream);

    deg_kernel<<<nbE, 256, 0, stream>>>(coli, E, deg);
    bscan_kernel<<<1, MAXNB, 0, stream>>>(deg, off, cursor, NB, E, N);
    bfill_kernel<<<(E + FCHUNK - 1) / FCHUNK, 256, 0, stream>>>(rowi, coli, cursor, ebuf, E, NB);
    gemm1_kernel<<<(N + 15) / 16, 256, 0, stream>>>(x, W1, deg, hs, N);

    phaseB_kernel<<<NB * S, 256, 0, stream>>>(ebuf, off, hs, accp, S, (int)NP);
    layer2_kernel<<<nbN, 256, 0, stream>>>(accp, hs, deg, b1, W2, hs2, S, (int)NP, N);
    phaseC_kernel<<<NB * S, 256, 0, stream>>>(ebuf, off, hs2, outp, S, (int)NP);
    fin2_kernel<<<nbN, 256, 0, stream>>>(outp, hs2, deg, b2, out, S, (int)NP, N);
}

// Round 6
// 652.153 us; speedup vs baseline: 1.1366x; 1.0008x over previous
//
#include <hip/hip_runtime.h>

#define N_FEAT 128
#define F1 16
#define F2 2
#define BSHIFT 7
#define BNODES 128        // nodes per bucket (dst >> 7)
#define MAXNB 1024        // scan capacity (NB = 782)
#define FCHUNK 8192       // edges per bfill block
#define SEG 4             // segments per bucket in phaseB/C

// ---------------- degree histogram over dst (no-return int atomics) ----------
__global__ void deg_kernel(const int* __restrict__ col, int E, int* __restrict__ deg) {
    int i = blockIdx.x * blockDim.x + threadIdx.x;
    if (i < E) atomicAdd(&deg[col[i]], 1);
}

// ---------------- bucket counts from deg + exclusive scan (1 block) ----------
__global__ __launch_bounds__(MAXNB) void bscan_kernel(const int* __restrict__ deg,
                                                      int* __restrict__ off,
                                                      int* __restrict__ cursor,
                                                      int NB, int E, int N) {
    __shared__ int s[MAXNB];
    int t = threadIdx.x;
    int v = 0;
    if (t < NB) {
        int base = t * BNODES;
        int lim = min(BNODES, N - base);
        for (int k = 0; k < lim; ++k) v += deg[base + k];
    }
    s[t] = v;
    __syncthreads();
    for (int o = 1; o < MAXNB; o <<= 1) {
        int u = (t >= o) ? s[t - o] : 0;
        __syncthreads();
        s[t] += u;
        __syncthreads();
    }
    if (t < NB) {
        int x = s[t] - v;   // exclusive
        off[t] = x;
        cursor[t] = x;
    }
    if (t == 0) off[NB] = E;
}

// ---------------- bucketed fill, unroll-8 placement --------------------------
__global__ __launch_bounds__(256) void bfill_kernel(const int* __restrict__ rowi,
                                                    const int* __restrict__ coli,
                                                    int* __restrict__ cursor,
                                                    unsigned int* __restrict__ ebuf,
                                                    int E, int NB) {
    __shared__ int h[MAXNB];
    __shared__ int baseL[MAXNB];
    int t = threadIdx.x;
    for (int i = t; i < NB; i += 256) h[i] = 0;
    __syncthreads();
    int s0 = blockIdx.x * FCHUNK;
    int e0 = min(s0 + FCHUNK, E);
    for (int i = s0 + t; i < e0; i += 256) atomicAdd(&h[coli[i] >> BSHIFT], 1);
    __syncthreads();
    for (int i = t; i < NB; i += 256) {
        int v = h[i];
        baseL[i] = v ? atomicAdd(&cursor[i], v) : 0;
        h[i] = 0;   // reuse as local rank
    }
    __syncthreads();
    for (int i0 = s0; i0 < e0; i0 += 2048) {
        int cc[8], rr[8];
#pragma unroll
        for (int j = 0; j < 8; ++j) {               // 16 loads in flight
            int idx = i0 + j * 256 + t;
            cc[j] = (idx < e0) ? coli[idx] : -1;
            rr[j] = (idx < e0) ? rowi[idx] : 0;
        }
#pragma unroll
        for (int j = 0; j < 8; ++j) {               // 8 independent LDS ret-atomics
            if (cc[j] >= 0) {
                int b = cc[j] >> BSHIFT;
                int r = atomicAdd(&h[b], 1);
                ebuf[baseL[b] + r] = ((unsigned)rr[j] << BSHIFT) | (unsigned)(cc[j] & (BNODES - 1));
            }
        }
    }
}

// ---------------- layer-1 GEMM: hs[r,f] = dinv[r] * sum_k x[r,k]*W1[k,f] -----
__global__ __launch_bounds__(256) void gemm1_kernel(
    const float* __restrict__ x, const float* __restrict__ W1,
    const int* __restrict__ deg, float* __restrict__ hs, int N) {
    __shared__ float ws[N_FEAT * F1];
    __shared__ float xs[16][132];       // padded
    int t = threadIdx.x;
    const float4* W14 = (const float4*)W1;
    for (int i = t; i < 512; i += 256) ((float4*)ws)[i] = W14[i];
    int row0 = blockIdx.x * 16;
    for (int i = t; i < 512; i += 256) {
        int r = i >> 5, k4 = i & 31;
        int row = row0 + r;
        float4 v = (row < N) ? ((const float4*)x)[row * 32 + k4] : make_float4(0.f, 0.f, 0.f, 0.f);
        *(float4*)&xs[r][k4 * 4] = v;
    }
    __syncthreads();
    int rr = t >> 4, f = t & 15;
    int row = row0 + rr;
    if (row < N) {
        float acc = 0.f;
#pragma unroll
        for (int k = 0; k < N_FEAT; ++k) acc += xs[rr][k] * ws[k * F1 + f];
        hs[row * F1 + f] = acc * rsqrtf((float)(deg[row] + 1));
    }
}

// ---------------- phase B: syncless gather, 32 loads in flight ---------------
__global__ __launch_bounds__(256) void phaseB_kernel(
    const unsigned int* __restrict__ ebuf, const int* __restrict__ off,
    const float* __restrict__ hs, float* __restrict__ acc) {
    __shared__ float accL[BNODES * 17];
    int t = threadIdx.x;
    int b = blockIdx.x >> 2;          // / SEG
    int seg = blockIdx.x & (SEG - 1);
    int s0 = off[b], s1 = off[b + 1];
    int cnt = s1 - s0;
    int len = (cnt + SEG - 1) / SEG;
    int base = s0 + seg * len;
    int end = min(base + len, s1);
    for (int i = t; i < BNODES * 17; i += 256) accL[i] = 0.f;
    __syncthreads();
    int g = t >> 4, f = t & 15;
    for (int k0 = base; k0 < end; k0 += 256) {
        if (k0 + 256 <= end) {
            unsigned u[16];
            float v[16];
#pragma unroll
            for (int j = 0; j < 16; ++j) u[j] = ebuf[k0 + j * 16 + g];   // broadcast-coalesced
#pragma unroll
            for (int j = 0; j < 16; ++j) v[j] = hs[(u[j] >> BSHIFT) * F1 + f];  // 64B/group
#pragma unroll
            for (int j = 0; j < 16; ++j)
                atomicAdd(&accL[(u[j] & (BNODES - 1)) * 17 + f], v[j]);
        } else {
            for (int j = 0; j < 16; ++j) {
                int idx = k0 + j * 16 + g;
                if (idx < end) {
                    unsigned u = ebuf[idx];
                    float v = hs[(u >> BSHIFT) * F1 + f];
                    atomicAdd(&accL[(u & (BNODES - 1)) * 17 + f], v);
                }
            }
        }
    }
    __syncthreads();
    // coalesced no-return global atomics into shared acc tile
    float* dst = acc + (size_t)b * BNODES * F1;
    for (int i = t; i < BNODES * F1; i += 256)
        atomicAdd(&dst[i], accL[(i >> 4) * 17 + (i & 15)]);
}

// ---------------- layer 2 prep: acc + self, relu, x W2 -----------------------
__global__ __launch_bounds__(256) void layer2_kernel(
    const float* __restrict__ acc, const float* __restrict__ hs,
    const int* __restrict__ deg, const float* __restrict__ b1,
    const float* __restrict__ W2, float* __restrict__ hs2, int N) {
    __shared__ float w2s[F1 * F2];
    __shared__ float b1s[F1];
    int t = threadIdx.x;
    if (t < F1 * F2) w2s[t] = W2[t];
    if (t < F1) b1s[t] = b1[t];
    __syncthreads();
    int i = blockIdx.x * blockDim.x + t;
    if (i >= N) return;
    float di = rsqrtf((float)(deg[i] + 1));
    const float4* a4 = (const float4*)(acc + (size_t)i * F1);
    const float4* s4 = (const float4*)(hs + (size_t)i * F1);
    float h0 = 0.f, h1 = 0.f;
#pragma unroll
    for (int q = 0; q < 4; ++q) {
        float4 a = a4[q], s = s4[q];
        float vv[4] = {a.x + s.x, a.y + s.y, a.z + s.z, a.w + s.w};
#pragma unroll
        for (int u = 0; u < 4; ++u) {
            int f = q * 4 + u;
            float o = fmaxf(di * vv[u] + b1s[f], 0.f);
            h0 += o * w2s[f * F2 + 0];
            h1 += o * w2s[f * F2 + 1];
        }
    }
    float2 r;
    r.x = h0 * di;
    r.y = h1 * di;
    ((float2*)hs2)[i] = r;
}

// ---------------- phase C: syncless, unroll-4, stride-3 LDS ------------------
__global__ __launch_bounds__(256) void phaseC_kernel(
    const unsigned int* __restrict__ ebuf, const int* __restrict__ off,
    const float* __restrict__ hs2, float* __restrict__ outacc) {
    __shared__ float o2[BNODES * 3];    // stride 3: spreads banks
    int t = threadIdx.x;
    int b = blockIdx.x >> 2;
    int seg = blockIdx.x & (SEG - 1);
    int s0 = off[b], s1 = off[b + 1];
    int cnt = s1 - s0;
    int len = (cnt + SEG - 1) / SEG;
    int base = s0 + seg * len;
    int end = min(base + len, s1);
    for (int i = t; i < BNODES * 3; i += 256) o2[i] = 0.f;
    __syncthreads();
    for (int k0 = base; k0 < end; k0 += 1024) {
        if (k0 + 1024 <= end) {
            unsigned u[4];
            float2 v[4];
#pragma unroll
            for (int j = 0; j < 4; ++j) u[j] = ebuf[k0 + j * 256 + t];
#pragma unroll
            for (int j = 0; j < 4; ++j) v[j] = ((const float2*)hs2)[u[j] >> BSHIFT];
#pragma unroll
            for (int j = 0; j < 4; ++j) {
                int dl = (int)(u[j] & (BNODES - 1));
                atomicAdd(&o2[dl * 3 + 0], v[j].x);
                atomicAdd(&o2[dl * 3 + 1], v[j].y);
            }
        } else {
            for (int j = 0; j < 4; ++j) {
                int idx = k0 + j * 256 + t;
                if (idx < end) {
                    unsigned u = ebuf[idx];
                    float2 v = ((const float2*)hs2)[u >> BSHIFT];
                    int dl = (int)(u & (BNODES - 1));
                    atomicAdd(&o2[dl * 3 + 0], v.x);
                    atomicAdd(&o2[dl * 3 + 1], v.y);
                }
            }
        }
    }
    __syncthreads();
    if (t < BNODES * F2)
        atomicAdd(&outacc[(size_t)b * BNODES * F2 + t], o2[(t >> 1) * 3 + (t & 1)]);
}

// ---------------- finalize layer 2 ------------------------------------------
__global__ void fin2_kernel(const float* __restrict__ outacc, const float* __restrict__ hs2,
                            const int* __restrict__ deg, const float* __restrict__ b2,
                            float* __restrict__ out, int N) {
    int i = blockIdx.x * blockDim.x + threadIdx.x;
    if (i >= N) return;
    float di = rsqrtf((float)(deg[i] + 1));
    float2 s = ((const float2*)hs2)[i];
    float2 p = ((const float2*)outacc)[i];
    float2 o;
    o.x = di * (p.x + s.x) + b2[0];
    o.y = di * (p.y + s.y) + b2[1];
    ((float2*)out)[i] = o;
}

extern "C" void kernel_launch(void* const* d_in, const int* in_sizes, int n_in,
                              void* d_out, int out_size, void* d_ws, size_t ws_size,
                              hipStream_t stream) {
    const float* x  = (const float*)d_in[0];
    const int*   ei = (const int*)d_in[1];
    const float* W1 = (const float*)d_in[2];
    const float* b1 = (const float*)d_in[3];
    const float* W2 = (const float*)d_in[4];
    const float* b2 = (const float*)d_in[5];
    int N = in_sizes[0] / N_FEAT;
    int E = in_sizes[1] / 2;
    const int* rowi = ei;        // src
    const int* coli = ei + E;    // dst
    float* out = (float*)d_out;

    int NB = (N + BNODES - 1) / BNODES;   // 782

    size_t NP = ((size_t)N + 1023) & ~(size_t)1023;
    size_t EP = ((size_t)E + 1023) & ~(size_t)1023;

    char* w = (char*)d_ws;
    int*          deg    = (int*)w;            w += NP * 4;
    int*          off    = (int*)w;            w += (MAXNB + 1) * 4;
    int*          cursor = (int*)w;            w += MAXNB * 4;
    float*        hs     = (float*)w;          w += NP * F1 * 4;
    float*        hs2    = (float*)w;          w += NP * F2 * 4;
    float*        acc    = (float*)w;          w += NP * F1 * 4;
    float*        outacc = (float*)w;          w += NP * F2 * 4;
    unsigned int* ebuf   = (unsigned int*)w;   w += EP * 4;

    int nbE = (E + 255) / 256;
    int nbN = (N + 255) / 256;

    hipMemsetAsync(deg, 0, (size_t)N * sizeof(int), stream);
    hipMemsetAsync(acc, 0, (size_t)N * F1 * sizeof(float), stream);
    hipMemsetAsync(outacc, 0, (size_t)N * F2 * sizeof(float), stream);

    deg_kernel<<<nbE, 256, 0, stream>>>(coli, E, deg);
    bscan_kernel<<<1, MAXNB, 0, stream>>>(deg, off, cursor, NB, E, N);
    bfill_kernel<<<(E + FCHUNK - 1) / FCHUNK, 256, 0, stream>>>(rowi, coli, cursor, ebuf, E, NB);
    gemm1_kernel<<<(N + 15) / 16, 256, 0, stream>>>(x, W1, deg, hs, N);

    phaseB_kernel<<<NB * SEG, 256, 0, stream>>>(ebuf, off, hs, acc);
    layer2_kernel<<<nbN, 256, 0, stream>>>(acc, hs, deg, b1, W2, hs2, N);
    phaseC_kernel<<<NB * SEG, 256, 0, stream>>>(ebuf, off, hs2, outacc);
    fin2_kernel<<<nbN, 256, 0, stream>>>(outacc, hs2, deg, b2, out, N);
}